// Round 2
// baseline (422.989 us; speedup 1.0000x reference)
//
#include <hip/hip_runtime.h>
#include <hip/hip_bf16.h>
#include <math.h>

#define N_NODES 50000
#define N_EDGES 800000
#define IN_CH 128
#define OUT_CH 64
#define BN_EPS 1e-5f
#define SCAN_THREADS 1024
#define SCAN_CHUNK 49  // 1024*49 = 50176 >= 50000

// ---------------- init: cnt = 0, sums = 0 ----------------
__global__ void init_kernel(int* __restrict__ cnt, float* __restrict__ sums, int N) {
    int i = blockIdx.x * blockDim.x + threadIdx.x;
    if (i < N) cnt[i] = 0;
    if (i < 128) sums[i] = 0.0f;
}

// ---------------- in-degree count over edge dst (int atomics) ----------------
__global__ void count_kernel(const int* __restrict__ edst, int* __restrict__ cnt, int E) {
    int i = blockIdx.x * blockDim.x + threadIdx.x;
    if (i < E) atomicAdd(&cnt[edst[i]], 1);
}

// ---------------- single-block exclusive scan; also dinv = rsqrt(cnt+1) ----------------
__global__ __launch_bounds__(SCAN_THREADS) void scan_kernel(const int* __restrict__ cnt,
                                                            int* __restrict__ offsets,
                                                            int* __restrict__ cursor,
                                                            float* __restrict__ dinv, int N) {
    __shared__ int lsum[SCAN_THREADS];
    int t = threadIdx.x;
    int begin = t * SCAN_CHUNK;
    int endi = begin + SCAN_CHUNK; if (endi > N) endi = N;
    int s = 0;
    for (int i = begin; i < endi; ++i) s += cnt[i];
    lsum[t] = s;
    __syncthreads();
    // Hillis-Steele inclusive scan
    for (int off = 1; off < SCAN_THREADS; off <<= 1) {
        int v = (t >= off) ? lsum[t - off] : 0;
        __syncthreads();
        lsum[t] += v;
        __syncthreads();
    }
    int base = (t == 0) ? 0 : lsum[t - 1];
    for (int i = begin; i < endi; ++i) {
        int c = cnt[i];
        offsets[i] = base;
        cursor[i] = base;
        dinv[i] = rsqrtf((float)(c + 1));  // +1 self-loop
        base += c;
    }
    if (t == SCAN_THREADS - 1) offsets[N] = lsum[SCAN_THREADS - 1];
}

// ---------------- fill buckets: bucket[pos] = src ----------------
__global__ void fill_kernel(const int* __restrict__ esrc, const int* __restrict__ edst,
                            int* __restrict__ cursor, int* __restrict__ bucket, int E) {
    int i = blockIdx.x * blockDim.x + threadIdx.x;
    if (i < E) {
        int d = edst[i];
        int pos = atomicAdd(&cursor[d], 1);
        bucket[pos] = esrc[i];
    }
}

// ---------------- GEMM: h[N,64] = x[N,128] @ W[128,64] ----------------
__global__ __launch_bounds__(256) void gemm_kernel(const float* __restrict__ x,
                                                   const float* __restrict__ W,
                                                   float* __restrict__ h, int N) {
    __shared__ float Wlds[IN_CH * OUT_CH];   // 32 KB
    __shared__ float xlds[16 * IN_CH];       // 8 KB
    int t = threadIdx.x;
    const float4* W4 = (const float4*)W;
    float4* Wl4 = (float4*)Wlds;
#pragma unroll
    for (int i = 0; i < 8; ++i) Wl4[t + 256 * i] = W4[t + 256 * i];

    int c = t & 63;
    int g = t >> 6;

    for (int tile = blockIdx.x; tile < N / 16; tile += gridDim.x) {
        int row0 = tile * 16;
        __syncthreads();
        const float4* xsrc = (const float4*)(x + (size_t)row0 * IN_CH);
        float4* xl4 = (float4*)xlds;
        xl4[t] = xsrc[t];
        xl4[t + 256] = xsrc[t + 256];
        __syncthreads();

        float acc0 = 0.f, acc1 = 0.f, acc2 = 0.f, acc3 = 0.f;
        const float4* xl4r = (const float4*)xlds;
#pragma unroll 4
        for (int k4 = 0; k4 < 32; ++k4) {
            float4 xv0 = xl4r[(g * 4 + 0) * 32 + k4];
            float4 xv1 = xl4r[(g * 4 + 1) * 32 + k4];
            float4 xv2 = xl4r[(g * 4 + 2) * 32 + k4];
            float4 xv3 = xl4r[(g * 4 + 3) * 32 + k4];
            const float* p0 = (const float*)&xv0;
            const float* p1 = (const float*)&xv1;
            const float* p2 = (const float*)&xv2;
            const float* p3 = (const float*)&xv3;
#pragma unroll
            for (int j = 0; j < 4; ++j) {
                float w = Wlds[(k4 * 4 + j) * OUT_CH + c];
                acc0 += p0[j] * w;
                acc1 += p1[j] * w;
                acc2 += p2[j] * w;
                acc3 += p3[j] * w;
            }
        }
        size_t base = (size_t)(row0 + g * 4) * OUT_CH + c;
        h[base + 0 * OUT_CH] = acc0;
        h[base + 1 * OUT_CH] = acc1;
        h[base + 2 * OUT_CH] = acc2;
        h[base + 3 * OUT_CH] = acc3;
    }
}

// ---------------- fused gather: agg + bias + tanh + BN-stat accumulation ----------------
// One wave per dst node; lane = output channel.
__global__ __launch_bounds__(256) void gather_fused_kernel(const int* __restrict__ offsets,
                                                           const int* __restrict__ bucket,
                                                           const float* __restrict__ dinv,
                                                           const float* __restrict__ h,
                                                           const float* __restrict__ bias,
                                                           float* __restrict__ out,
                                                           float* __restrict__ sums, int N) {
    int t = threadIdx.x;
    int lane = t & 63;
    int wid = (blockIdx.x * blockDim.x + t) >> 6;
    int nw = (gridDim.x * blockDim.x) >> 6;
    float bias_c = bias[lane];
    float ssum = 0.f, ssq = 0.f;

    for (int d = wid; d < N; d += nw) {
        float dd = dinv[d];
        float acc = h[(size_t)d * OUT_CH + lane] * dd * dd;  // self-loop
        int b0 = offsets[d], b1 = offsets[d + 1];
        for (int base = b0; base < b1; base += 64) {
            int idx = base + lane;
            int sv = 0; float dv = 0.f;
            if (idx < b1) { sv = bucket[idx]; dv = dinv[sv]; }
            int m = b1 - base; if (m > 64) m = 64;
            int j = 0;
            for (; j + 3 < m; j += 4) {
                int s0 = __shfl(sv, j + 0); float w0 = __shfl(dv, j + 0);
                int s1 = __shfl(sv, j + 1); float w1 = __shfl(dv, j + 1);
                int s2 = __shfl(sv, j + 2); float w2 = __shfl(dv, j + 2);
                int s3 = __shfl(sv, j + 3); float w3 = __shfl(dv, j + 3);
                float h0 = h[(size_t)s0 * OUT_CH + lane];
                float h1 = h[(size_t)s1 * OUT_CH + lane];
                float h2 = h[(size_t)s2 * OUT_CH + lane];
                float h3 = h[(size_t)s3 * OUT_CH + lane];
                acc += h0 * (w0 * dd);
                acc += h1 * (w1 * dd);
                acc += h2 * (w2 * dd);
                acc += h3 * (w3 * dd);
            }
            for (; j < m; ++j) {
                int s = __shfl(sv, j);
                float w = __shfl(dv, j) * dd;
                acc += h[(size_t)s * OUT_CH + lane] * w;
            }
        }
        float v = tanhf(acc + bias_c);
        out[(size_t)d * OUT_CH + lane] = v;
        ssum += v;
        ssq += v * v;
    }

    __shared__ float ls[256];
    __shared__ float ls2[256];
    ls[t] = ssum; ls2[t] = ssq;
    __syncthreads();
    if (t < 128) { ls[t] += ls[t + 128]; ls2[t] += ls2[t + 128]; }
    __syncthreads();
    if (t < 64) {
        atomicAdd(&sums[t], ls[t] + ls[t + 64]);
        atomicAdd(&sums[64 + t], ls2[t] + ls2[t + 64]);
    }
}

// ---------------- BN apply in place ----------------
__global__ __launch_bounds__(256) void bn_apply_kernel(float* __restrict__ a,
                                                       const float* __restrict__ sums,
                                                       const float* __restrict__ gamma,
                                                       const float* __restrict__ beta, int N) {
    int c = threadIdx.x & 63;
    const float invN = 1.0f / (float)N_NODES;
    float mean = sums[c] * invN;
    float var = sums[64 + c] * invN - mean * mean;
    float scale = gamma[c] * rsqrtf(var + BN_EPS);
    float shift = beta[c] - mean * scale;
    size_t total = (size_t)gridDim.x * blockDim.x;
    for (size_t idx = (size_t)blockIdx.x * blockDim.x + threadIdx.x; idx < (size_t)N * OUT_CH; idx += total) {
        a[idx] = a[idx] * scale + shift;
    }
}

extern "C" void kernel_launch(void* const* d_in, const int* in_sizes, int n_in,
                              void* d_out, int out_size, void* d_ws, size_t ws_size,
                              hipStream_t stream) {
    const float* x     = (const float*)d_in[0];
    const int*   eidx  = (const int*)d_in[1];   // [2, E] flat: src row then dst row
    const float* W     = (const float*)d_in[2];
    const float* bias  = (const float*)d_in[3];
    const float* gamma = (const float*)d_in[4];
    const float* beta  = (const float*)d_in[5];
    float* out = (float*)d_out;

    const int* esrc = eidx;
    const int* edst = eidx + N_EDGES;

    // workspace layout:
    // h[N*64] f32 | cnt[N] i32 | offsets[N+1] i32 | cursor[N] i32 | dinv[N] f32
    // | sums[128] f32 | bucket[E] i32
    float* h      = (float*)d_ws;
    int*   cnt    = (int*)(h + (size_t)N_NODES * OUT_CH);
    int*   offs   = cnt + N_NODES;
    int*   cursor = offs + (N_NODES + 1);
    float* dinv   = (float*)(cursor + N_NODES);
    float* sums   = dinv + N_NODES;
    int*   bucket = (int*)(sums + 128);

    init_kernel<<<(N_NODES + 255) / 256, 256, 0, stream>>>(cnt, sums, N_NODES);
    count_kernel<<<(N_EDGES + 255) / 256, 256, 0, stream>>>(edst, cnt, N_EDGES);
    scan_kernel<<<1, SCAN_THREADS, 0, stream>>>(cnt, offs, cursor, dinv, N_NODES);
    fill_kernel<<<(N_EDGES + 255) / 256, 256, 0, stream>>>(esrc, edst, cursor, bucket, N_EDGES);
    gemm_kernel<<<N_NODES / 16, 256, 0, stream>>>(x, W, h, N_NODES);
    gather_fused_kernel<<<2048, 256, 0, stream>>>(offs, bucket, dinv, h, bias, out, sums, N_NODES);
    bn_apply_kernel<<<512, 256, 0, stream>>>(out, sums, gamma, beta, N_NODES);
}

// Round 3
// 296.502 us; speedup vs baseline: 1.4266x; 1.4266x over previous
//
#include <hip/hip_runtime.h>
#include <hip/hip_bf16.h>
#include <math.h>

#define N_NODES 50000
#define N_EDGES 800000
#define IN_CH 128
#define OUT_CH 64
#define BN_EPS 1e-5f
#define NB_SCAN 196  // ceil(50000/256)

// ---------------- init: cnt = 0, sums = 0 ----------------
__global__ void init_kernel(int* __restrict__ cnt, float* __restrict__ sums, int N) {
    int i = blockIdx.x * blockDim.x + threadIdx.x;
    if (i < N) cnt[i] = 0;
    if (i < 128) sums[i] = 0.0f;
}

// ---------------- in-degree count over edge dst (int atomics) ----------------
__global__ void count_kernel(const int* __restrict__ edst, int* __restrict__ cnt, int E) {
    int i = blockIdx.x * blockDim.x + threadIdx.x;
    if (i < E) atomicAdd(&cnt[edst[i]], 1);
}

// ---------------- hierarchical scan stage 1: per-block sums ----------------
__global__ __launch_bounds__(256) void blocksum_kernel(const int* __restrict__ cnt,
                                                       int* __restrict__ bsum, int N) {
    __shared__ int ls[256];
    int t = threadIdx.x;
    int i = blockIdx.x * 256 + t;
    ls[t] = (i < N) ? cnt[i] : 0;
    __syncthreads();
#pragma unroll
    for (int off = 128; off > 0; off >>= 1) {
        if (t < off) ls[t] += ls[t + off];
        __syncthreads();
    }
    if (t == 0) bsum[blockIdx.x] = ls[0];
}

// ---------------- stage 2: exclusive scan of block sums (single tiny block) ----------------
__global__ __launch_bounds__(256) void scan_bsums_kernel(int* __restrict__ bsum, int NB) {
    __shared__ int ls[256];
    int t = threadIdx.x;
    int v = (t < NB) ? bsum[t] : 0;
    ls[t] = v;
    __syncthreads();
    for (int off = 1; off < 256; off <<= 1) {
        int u = (t >= off) ? ls[t - off] : 0;
        __syncthreads();
        ls[t] += u;
        __syncthreads();
    }
    if (t < NB) bsum[t] = ls[t] - v;  // exclusive
}

// ---------------- stage 3: per-element offsets, cursor, dinv ----------------
__global__ __launch_bounds__(256) void offsets_kernel(const int* __restrict__ cnt,
                                                      const int* __restrict__ bsum,
                                                      int* __restrict__ offsets,
                                                      int* __restrict__ cursor,
                                                      float* __restrict__ dinv, int N, int E) {
    __shared__ int ls[256];
    int t = threadIdx.x;
    int i = blockIdx.x * 256 + t;
    int c = (i < N) ? cnt[i] : 0;
    ls[t] = c;
    __syncthreads();
    for (int off = 1; off < 256; off <<= 1) {
        int u = (t >= off) ? ls[t - off] : 0;
        __syncthreads();
        ls[t] += u;
        __syncthreads();
    }
    if (i < N) {
        int excl = ls[t] - c + bsum[blockIdx.x];
        offsets[i] = excl;
        cursor[i] = excl;
        dinv[i] = rsqrtf((float)(c + 1));  // +1 self-loop
        if (i == N - 1) offsets[N] = E;
    }
}

// ---------------- fill buckets: bucket[pos] = src ----------------
__global__ void fill_kernel(const int* __restrict__ esrc, const int* __restrict__ edst,
                            int* __restrict__ cursor, int* __restrict__ bucket, int E) {
    int i = blockIdx.x * blockDim.x + threadIdx.x;
    if (i < E) {
        int d = edst[i];
        int pos = atomicAdd(&cursor[d], 1);
        bucket[pos] = esrc[i];
    }
}

// ---------------- GEMM: h[N,64] = x[N,128] @ W[128,64] ----------------
__global__ __launch_bounds__(256) void gemm_kernel(const float* __restrict__ x,
                                                   const float* __restrict__ W,
                                                   float* __restrict__ h, int N) {
    __shared__ float Wlds[IN_CH * OUT_CH];   // 32 KB
    __shared__ float xlds[16 * IN_CH];       // 8 KB
    int t = threadIdx.x;
    const float4* W4 = (const float4*)W;
    float4* Wl4 = (float4*)Wlds;
#pragma unroll
    for (int i = 0; i < 8; ++i) Wl4[t + 256 * i] = W4[t + 256 * i];

    int c = t & 63;
    int g = t >> 6;

    for (int tile = blockIdx.x; tile < N / 16; tile += gridDim.x) {
        int row0 = tile * 16;
        __syncthreads();
        const float4* xsrc = (const float4*)(x + (size_t)row0 * IN_CH);
        float4* xl4 = (float4*)xlds;
        xl4[t] = xsrc[t];
        xl4[t + 256] = xsrc[t + 256];
        __syncthreads();

        float acc0 = 0.f, acc1 = 0.f, acc2 = 0.f, acc3 = 0.f;
        const float4* xl4r = (const float4*)xlds;
#pragma unroll 4
        for (int k4 = 0; k4 < 32; ++k4) {
            float4 xv0 = xl4r[(g * 4 + 0) * 32 + k4];
            float4 xv1 = xl4r[(g * 4 + 1) * 32 + k4];
            float4 xv2 = xl4r[(g * 4 + 2) * 32 + k4];
            float4 xv3 = xl4r[(g * 4 + 3) * 32 + k4];
            const float* p0 = (const float*)&xv0;
            const float* p1 = (const float*)&xv1;
            const float* p2 = (const float*)&xv2;
            const float* p3 = (const float*)&xv3;
#pragma unroll
            for (int j = 0; j < 4; ++j) {
                float w = Wlds[(k4 * 4 + j) * OUT_CH + c];
                acc0 += p0[j] * w;
                acc1 += p1[j] * w;
                acc2 += p2[j] * w;
                acc3 += p3[j] * w;
            }
        }
        size_t base = (size_t)(row0 + g * 4) * OUT_CH + c;
        h[base + 0 * OUT_CH] = acc0;
        h[base + 1 * OUT_CH] = acc1;
        h[base + 2 * OUT_CH] = acc2;
        h[base + 3 * OUT_CH] = acc3;
    }
}

// ---------------- fused gather: agg + bias + tanh + BN-stat accumulation ----------------
__global__ __launch_bounds__(256) void gather_fused_kernel(const int* __restrict__ offsets,
                                                           const int* __restrict__ bucket,
                                                           const float* __restrict__ dinv,
                                                           const float* __restrict__ h,
                                                           const float* __restrict__ bias,
                                                           float* __restrict__ out,
                                                           float* __restrict__ sums, int N) {
    int t = threadIdx.x;
    int lane = t & 63;
    int wid = (blockIdx.x * blockDim.x + t) >> 6;
    int nw = (gridDim.x * blockDim.x) >> 6;
    float bias_c = bias[lane];
    float ssum = 0.f, ssq = 0.f;

    for (int d = wid; d < N; d += nw) {
        float dd = dinv[d];
        float acc = h[(size_t)d * OUT_CH + lane] * dd * dd;  // self-loop
        int b0 = offsets[d], b1 = offsets[d + 1];
        for (int base = b0; base < b1; base += 64) {
            int idx = base + lane;
            int sv = 0; float dv = 0.f;
            if (idx < b1) { sv = bucket[idx]; dv = dinv[sv]; }
            int m = b1 - base; if (m > 64) m = 64;
            int j = 0;
            for (; j + 3 < m; j += 4) {
                int s0 = __shfl(sv, j + 0); float w0 = __shfl(dv, j + 0);
                int s1 = __shfl(sv, j + 1); float w1 = __shfl(dv, j + 1);
                int s2 = __shfl(sv, j + 2); float w2 = __shfl(dv, j + 2);
                int s3 = __shfl(sv, j + 3); float w3 = __shfl(dv, j + 3);
                float h0 = h[(size_t)s0 * OUT_CH + lane];
                float h1 = h[(size_t)s1 * OUT_CH + lane];
                float h2 = h[(size_t)s2 * OUT_CH + lane];
                float h3 = h[(size_t)s3 * OUT_CH + lane];
                acc += h0 * (w0 * dd);
                acc += h1 * (w1 * dd);
                acc += h2 * (w2 * dd);
                acc += h3 * (w3 * dd);
            }
            for (; j < m; ++j) {
                int s = __shfl(sv, j);
                float w = __shfl(dv, j) * dd;
                acc += h[(size_t)s * OUT_CH + lane] * w;
            }
        }
        float v = tanhf(acc + bias_c);
        out[(size_t)d * OUT_CH + lane] = v;
        ssum += v;
        ssq += v * v;
    }

    __shared__ float ls[256];
    __shared__ float ls2[256];
    ls[t] = ssum; ls2[t] = ssq;
    __syncthreads();
    if (t < 128) { ls[t] += ls[t + 128]; ls2[t] += ls2[t + 128]; }
    __syncthreads();
    if (t < 64) {
        atomicAdd(&sums[t], ls[t] + ls[t + 64]);
        atomicAdd(&sums[64 + t], ls2[t] + ls2[t + 64]);
    }
}

// ---------------- BN apply in place ----------------
__global__ __launch_bounds__(256) void bn_apply_kernel(float* __restrict__ a,
                                                       const float* __restrict__ sums,
                                                       const float* __restrict__ gamma,
                                                       const float* __restrict__ beta, int N) {
    int c = threadIdx.x & 63;
    const float invN = 1.0f / (float)N_NODES;
    float mean = sums[c] * invN;
    float var = sums[64 + c] * invN - mean * mean;
    float scale = gamma[c] * rsqrtf(var + BN_EPS);
    float shift = beta[c] - mean * scale;
    size_t total = (size_t)gridDim.x * blockDim.x;
    for (size_t idx = (size_t)blockIdx.x * blockDim.x + threadIdx.x; idx < (size_t)N * OUT_CH; idx += total) {
        a[idx] = a[idx] * scale + shift;
    }
}

extern "C" void kernel_launch(void* const* d_in, const int* in_sizes, int n_in,
                              void* d_out, int out_size, void* d_ws, size_t ws_size,
                              hipStream_t stream) {
    const float* x     = (const float*)d_in[0];
    const int*   eidx  = (const int*)d_in[1];   // [2, E] flat: src row then dst row
    const float* W     = (const float*)d_in[2];
    const float* bias  = (const float*)d_in[3];
    const float* gamma = (const float*)d_in[4];
    const float* beta  = (const float*)d_in[5];
    float* out = (float*)d_out;

    const int* esrc = eidx;
    const int* edst = eidx + N_EDGES;

    // workspace layout:
    // h[N*64] f32 | cnt[N] i32 | offsets[N+1] i32 | cursor[N] i32 | dinv[N] f32
    // | sums[128] f32 | bsum[NB_SCAN] i32 | bucket[E] i32
    float* h      = (float*)d_ws;
    int*   cnt    = (int*)(h + (size_t)N_NODES * OUT_CH);
    int*   offs   = cnt + N_NODES;
    int*   cursor = offs + (N_NODES + 1);
    float* dinv   = (float*)(cursor + N_NODES);
    float* sums   = dinv + N_NODES;
    int*   bsum   = (int*)(sums + 128);
    int*   bucket = bsum + NB_SCAN;

    init_kernel<<<(N_NODES + 255) / 256, 256, 0, stream>>>(cnt, sums, N_NODES);
    count_kernel<<<(N_EDGES + 255) / 256, 256, 0, stream>>>(edst, cnt, N_EDGES);
    blocksum_kernel<<<NB_SCAN, 256, 0, stream>>>(cnt, bsum, N_NODES);
    scan_bsums_kernel<<<1, 256, 0, stream>>>(bsum, NB_SCAN);
    offsets_kernel<<<NB_SCAN, 256, 0, stream>>>(cnt, bsum, offs, cursor, dinv, N_NODES, N_EDGES);
    fill_kernel<<<(N_EDGES + 255) / 256, 256, 0, stream>>>(esrc, edst, cursor, bucket, N_EDGES);
    gemm_kernel<<<N_NODES / 16, 256, 0, stream>>>(x, W, h, N_NODES);
    gather_fused_kernel<<<2048, 256, 0, stream>>>(offs, bucket, dinv, h, bias, out, sums, N_NODES);
    bn_apply_kernel<<<512, 256, 0, stream>>>(out, sums, gamma, beta, N_NODES);
}